// Round 4
// baseline (696.692 us; speedup 1.0000x reference)
//
#include <hip/hip_runtime.h>

#define D 64
#define NPB 256              // nodes per bucket (dstLocal fits in 8 bits)
#define MAXB 512             // LDS bound on bucket count; B = ceil(N/NPB) must be <= MAXB
#define SCATTER_BLOCKS 256
#define SCATTER_T 256

// ---------------------------------------------------------------------------
// zero helpers (ws is poisoned 0xAA every launch)
// ---------------------------------------------------------------------------
__global__ void zero_i_kernel(int* __restrict__ p, int n) {
    int i = blockIdx.x * blockDim.x + threadIdx.x;
    if (i < n) p[i] = 0;
}
__global__ void zero_f4_kernel(float4* __restrict__ p, int n4) {
    int i = blockIdx.x * blockDim.x + threadIdx.x;
    if (i < n4) p[i] = make_float4(0.f, 0.f, 0.f, 0.f);
}

// ---------------------------------------------------------------------------
// bucket histogram: LDS-staged, then one global atomic per (block,bucket)
// ---------------------------------------------------------------------------
__global__ __launch_bounds__(SCATTER_T) void hist_bucket_kernel(const int* __restrict__ dst,
                                                                int* __restrict__ cnt,
                                                                int E, int B) {
    __shared__ int lc[MAXB];
    for (int i = threadIdx.x; i < B; i += blockDim.x) lc[i] = 0;
    __syncthreads();
    int chunk = (E + gridDim.x - 1) / gridDim.x;
    int lo = blockIdx.x * chunk, hi = min(lo + chunk, E);
    for (int e = lo + threadIdx.x; e < hi; e += blockDim.x)
        atomicAdd(&lc[dst[e] >> 8], 1);
    __syncthreads();
    for (int i = threadIdx.x; i < B; i += blockDim.x)
        if (lc[i]) atomicAdd(&cnt[i], lc[i]);
}

// ---------------------------------------------------------------------------
// exclusive scan of bucket counts (single block; B <= MAXB = 512)
// writes bucketStart[0..B] and cursor[0..B)
// ---------------------------------------------------------------------------
__global__ __launch_bounds__(MAXB) void scan_bucket_kernel(const int* __restrict__ cnt,
                                                           int* __restrict__ bucketStart,
                                                           int* __restrict__ cursor,
                                                           int B, int E) {
    __shared__ int sd[MAXB];
    int t = threadIdx.x;
    sd[t] = (t < B) ? cnt[t] : 0;
    __syncthreads();
    for (int st = 1; st < MAXB; st <<= 1) {
        int v = (t >= st) ? sd[t - st] : 0;
        __syncthreads();
        sd[t] += v;
        __syncthreads();
    }
    if (t < B) {
        int ex = (t == 0) ? 0 : sd[t - 1];
        bucketStart[t] = ex;
        cursor[t] = ex;
    }
    if (t == 0) bucketStart[B] = E;
}

// ---------------------------------------------------------------------------
// bucket scatter: two-pass per block. Phase1 LDS histogram of chunk;
// Phase2 reserve contiguous per-bucket ranges (1 global atomic per
// block x bucket); Phase3 write entries. A block's ~12 entries/bucket land
// contiguously (~96B runs) so L2 merges the line writes (vs 64B/entry before).
// Entry packing: x = src | dstLocal<<20 (needs N < 2^20), y = w bits.
// ---------------------------------------------------------------------------
__global__ __launch_bounds__(SCATTER_T) void bucket_scatter_kernel(
        const int* __restrict__ src, const int* __restrict__ dst,
        const float* __restrict__ w, int* __restrict__ cursor,
        int2* __restrict__ adjB, int E, int B) {
    __shared__ int lc[MAXB];
    __shared__ int lbase[MAXB];
    __shared__ int lfill[MAXB];
    int chunk = (E + gridDim.x - 1) / gridDim.x;
    int lo = blockIdx.x * chunk, hi = min(lo + chunk, E);
    for (int i = threadIdx.x; i < B; i += blockDim.x) { lc[i] = 0; lfill[i] = 0; }
    __syncthreads();
    for (int e = lo + threadIdx.x; e < hi; e += blockDim.x)
        atomicAdd(&lc[dst[e] >> 8], 1);
    __syncthreads();
    for (int i = threadIdx.x; i < B; i += blockDim.x)
        lbase[i] = lc[i] ? atomicAdd(&cursor[i], lc[i]) : 0;
    __syncthreads();
    for (int e = lo + threadIdx.x; e < hi; e += blockDim.x) {
        int t = dst[e];
        int b = t >> 8;
        int pos = lbase[b] + atomicAdd(&lfill[b], 1);
        adjB[pos] = make_int2(src[e] | ((t & (NPB - 1)) << 20), __float_as_int(w[e]));
    }
}

// ---------------------------------------------------------------------------
// Tiled row GEMM: out = A @ theta (N x 64 @ 64 x 64). (unchanged from r3)
// ---------------------------------------------------------------------------
__global__ __launch_bounds__(256) void rowgemm_kernel(const float* __restrict__ A,
                                                      const float* __restrict__ theta,
                                                      float* __restrict__ out, int N) {
    __shared__ float th[D * D];
    __shared__ float at[D][68];
    int t = threadIdx.x;
    int rowBase = blockIdx.x * 64;

#pragma unroll
    for (int i = 0; i < 4; ++i) {
        int f = t + i * 256;
        ((float4*)th)[f] = ((const float4*)theta)[f];
    }
#pragma unroll
    for (int i = 0; i < 4; ++i) {
        int f = t + i * 256;
        int row = f >> 4;
        int kv = f & 15;
        float4 v = make_float4(0.f, 0.f, 0.f, 0.f);
        if (rowBase + row < N) v = *(const float4*)&A[(size_t)(rowBase + row) * D + kv * 4];
        at[kv * 4 + 0][row] = v.x;
        at[kv * 4 + 1][row] = v.y;
        at[kv * 4 + 2][row] = v.z;
        at[kv * 4 + 3][row] = v.w;
    }
    __syncthreads();

    int c0 = (t & 15) * 4;
    int r0 = (t >> 4) * 4;
    float4 acc0 = make_float4(0.f, 0.f, 0.f, 0.f);
    float4 acc1 = acc0, acc2 = acc0, acc3 = acc0;

#pragma unroll
    for (int k = 0; k < D; ++k) {
        float4 bv = *(const float4*)&th[k * D + c0];
        float4 av = *(const float4*)&at[k][r0];
        acc0.x += av.x * bv.x; acc0.y += av.x * bv.y; acc0.z += av.x * bv.z; acc0.w += av.x * bv.w;
        acc1.x += av.y * bv.x; acc1.y += av.y * bv.y; acc1.z += av.y * bv.z; acc1.w += av.y * bv.w;
        acc2.x += av.z * bv.x; acc2.y += av.z * bv.y; acc2.z += av.z * bv.z; acc2.w += av.z * bv.w;
        acc3.x += av.w * bv.x; acc3.y += av.w * bv.y; acc3.z += av.w * bv.z; acc3.w += av.w * bv.w;
    }

    float4 accs[4] = {acc0, acc1, acc2, acc3};
#pragma unroll
    for (int i = 0; i < 4; ++i) {
        int r = rowBase + r0 + i;
        if (r < N) *(float4*)&out[(size_t)r * D + c0] = accs[i];
    }
}

// ---------------------------------------------------------------------------
// bucket gather: one block per bucket. 64KB LDS tile agg[NPB][64].
// Edges loaded 64/wave coalesced; entries broadcast via v_readlane (VALU,
// keeps the DS pipe free); accumulate with ds_add_f32 (lane d -> bank d%32,
// 2-way alias = free). Tile written out coalesced.
// ---------------------------------------------------------------------------
__global__ __launch_bounds__(512) void bucket_gather_kernel(
        const int* __restrict__ bucketStart, const int2* __restrict__ adjB,
        const float* __restrict__ proj, float* __restrict__ out, int N) {
    __shared__ float agg[NPB * D];   // 64 KB
    int t = threadIdx.x;
    float4* a4 = (float4*)agg;
#pragma unroll
    for (int i = 0; i < (NPB * D / 4) / 512; ++i)
        a4[t + i * 512] = make_float4(0.f, 0.f, 0.f, 0.f);
    __syncthreads();

    int b = blockIdx.x;
    int beg = bucketStart[b], end = bucketStart[b + 1];
    int lane = t & 63, wv = t >> 6;

    for (int base = beg + wv * 64; base < end; base += 512) {
        int cnt = min(64, end - base);
        if (cnt == 64) {
            int2 a = adjB[base + lane];      // one coalesced 8B/lane load
#pragma unroll
            for (int j = 0; j < 64; ++j) {
                int   xj = __builtin_amdgcn_readlane(a.x, j);
                float wj = __int_as_float(__builtin_amdgcn_readlane(a.y, j));
                int s  = xj & 0xFFFFF;
                int dL = ((unsigned)xj) >> 20;
                atomicAdd(&agg[dL * D + lane], wj * proj[(size_t)s * D + lane]);
            }
        } else {
            int2 a = make_int2(0, 0);
            if (lane < cnt) a = adjB[base + lane];
            for (int j = 0; j < cnt; ++j) {
                int   xj = __shfl(a.x, j, 64);
                float wj = __shfl(__int_as_float(a.y), j, 64);
                int s  = xj & 0xFFFFF;
                int dL = ((unsigned)xj) >> 20;
                atomicAdd(&agg[dL * D + lane], wj * proj[(size_t)s * D + lane]);
            }
        }
    }
    __syncthreads();

    int nodeBase = b * NPB;
#pragma unroll
    for (int i = 0; i < (NPB * (D / 4)) / 512; ++i) {
        int f = t + i * 512;
        int row = f >> 4;
        int node = nodeBase + row;
        if (node < N)
            *(float4*)&out[(size_t)node * D + (f & 15) * 4] = a4[f];
    }
}

// ---------------------------------------------------------------------------
// fallback scatter if ws too small / N too big for packing
// ---------------------------------------------------------------------------
__global__ void scatter_kernel(const int* __restrict__ src, const int* __restrict__ dst,
                               const float* __restrict__ w, const float* __restrict__ data,
                               float* __restrict__ agg, int E) {
    int tid = blockIdx.x * blockDim.x + threadIdx.x;
    int e = tid >> 6;
    int d = tid & 63;
    if (e >= E) return;
    float val = w[e] * data[(size_t)src[e] * D + d];
    atomicAdd(&agg[(size_t)dst[e] * D + d], val);
}

extern "C" void kernel_launch(void* const* d_in, const int* in_sizes, int n_in,
                              void* d_out, int out_size, void* d_ws, size_t ws_size,
                              hipStream_t stream) {
    const int*   src   = (const int*)d_in[0];
    const int*   dst   = (const int*)d_in[1];
    const float* w     = (const float*)d_in[2];
    const float* data  = (const float*)d_in[3];
    const float* theta = (const float*)d_in[4];
    const int E = in_sizes[0];
    const int N = in_sizes[3] / D;
    float* out = (float*)d_out;

    const int B = (N + NPB - 1) / NPB;

    // ws layout: proj | adjB | cnt[B] | bucketStart[B+1] | cursor[B]
    size_t need = (size_t)N * D * 4 + (size_t)E * 8 + ((size_t)3 * B + 2) * 4 + 256;

    if (ws_size >= need && N < (1 << 20) && B <= MAXB) {
        float* proj        = (float*)d_ws;
        int2*  adjB        = (int2*)(proj + (size_t)N * D);
        int*   cnt         = (int*)(adjB + E);
        int*   bucketStart = cnt + B;
        int*   cursor      = bucketStart + (B + 1);

        zero_i_kernel<<<(B + 255) / 256, 256, 0, stream>>>(cnt, B);
        hist_bucket_kernel<<<SCATTER_BLOCKS, SCATTER_T, 0, stream>>>(dst, cnt, E, B);
        scan_bucket_kernel<<<1, MAXB, 0, stream>>>(cnt, bucketStart, cursor, B, E);
        bucket_scatter_kernel<<<SCATTER_BLOCKS, SCATTER_T, 0, stream>>>(src, dst, w, cursor, adjB, E, B);
        rowgemm_kernel<<<(N + 63) / 64, 256, 0, stream>>>(data, theta, proj, N);
        bucket_gather_kernel<<<B, 512, 0, stream>>>(bucketStart, adjB, proj, out, N);
    } else {
        float* agg = (float*)d_ws;
        int n4 = (N * D) / 4;
        zero_f4_kernel<<<(n4 + 255) / 256, 256, 0, stream>>>((float4*)agg, n4);
        long long total = (long long)E * D;
        scatter_kernel<<<(int)((total + 255) / 256), 256, 0, stream>>>(src, dst, w, data, agg, E);
        rowgemm_kernel<<<(N + 63) / 64, 256, 0, stream>>>(agg, theta, out, N);
    }
}

// Round 5
// 239.973 us; speedup vs baseline: 2.9032x; 2.9032x over previous
//
#include <hip/hip_runtime.h>

#define D 64
#define NPB 128              // nodes per bucket (dstLocal: 7 bits)
#define NPB_SHIFT 7
#define MAXB 1024            // bound on bucket count B = ceil(N/NPB)
#define SCATTER_BLOCKS 256
#define SCATTER_T 256

// round-to-nearest-even fp32 -> bf16 (values are finite/normal here)
__device__ inline unsigned f2bf(float f) {
    unsigned u = __float_as_uint(f);
    return (u + 0x7FFFu + ((u >> 16) & 1u)) >> 16;
}

// ---------------------------------------------------------------------------
// zero helpers (ws is poisoned 0xAA every launch)
// ---------------------------------------------------------------------------
__global__ void zero_i_kernel(int* __restrict__ p, int n) {
    int i = blockIdx.x * blockDim.x + threadIdx.x;
    if (i < n) p[i] = 0;
}
__global__ void zero_f4_kernel(float4* __restrict__ p, int n4) {
    int i = blockIdx.x * blockDim.x + threadIdx.x;
    if (i < n4) p[i] = make_float4(0.f, 0.f, 0.f, 0.f);
}

// ---------------------------------------------------------------------------
// bucket histogram: LDS-staged, then one global atomic per (block,bucket)
// ---------------------------------------------------------------------------
__global__ __launch_bounds__(SCATTER_T) void hist_bucket_kernel(const int* __restrict__ dst,
                                                                int* __restrict__ cnt,
                                                                int E, int B) {
    __shared__ int lc[MAXB];
    for (int i = threadIdx.x; i < B; i += blockDim.x) lc[i] = 0;
    __syncthreads();
    int chunk = (E + gridDim.x - 1) / gridDim.x;
    int lo = blockIdx.x * chunk, hi = min(lo + chunk, E);
    for (int e = lo + threadIdx.x; e < hi; e += blockDim.x)
        atomicAdd(&lc[dst[e] >> NPB_SHIFT], 1);
    __syncthreads();
    for (int i = threadIdx.x; i < B; i += blockDim.x)
        if (lc[i]) atomicAdd(&cnt[i], lc[i]);
}

// ---------------------------------------------------------------------------
// exclusive scan of bucket counts (single block of MAXB threads)
// writes bucketStart[0..B], cursor[0..B), rowStart[N] = E
// ---------------------------------------------------------------------------
__global__ __launch_bounds__(MAXB) void scan_bucket_kernel(const int* __restrict__ cnt,
                                                           int* __restrict__ bucketStart,
                                                           int* __restrict__ cursor,
                                                           int* __restrict__ rowStartN,
                                                           int B, int E) {
    __shared__ int sd[MAXB];
    int t = threadIdx.x;
    sd[t] = (t < B) ? cnt[t] : 0;
    __syncthreads();
    for (int st = 1; st < MAXB; st <<= 1) {
        int v = (t >= st) ? sd[t - st] : 0;
        __syncthreads();
        sd[t] += v;
        __syncthreads();
    }
    if (t < B) {
        int ex = (t == 0) ? 0 : sd[t - 1];
        bucketStart[t] = ex;
        cursor[t] = ex;
    }
    if (t == 0) { bucketStart[B] = E; *rowStartN = E; }
}

// ---------------------------------------------------------------------------
// bucket scatter (two-pass per block, same scheme that passed in r4):
// LDS chunk histogram -> reserve contiguous per-bucket ranges (1 global
// atomic per block x bucket) -> write. Entries land in ~48-96B contiguous
// runs so L2 merges lines. Packing: x = src | dstLocal<<20, y = w bits.
// ---------------------------------------------------------------------------
__global__ __launch_bounds__(SCATTER_T) void bucket_scatter_kernel(
        const int* __restrict__ src, const int* __restrict__ dst,
        const float* __restrict__ w, int* __restrict__ cursor,
        int2* __restrict__ adjB, int E, int B) {
    __shared__ int lc[MAXB];
    __shared__ int lbase[MAXB];
    __shared__ int lfill[MAXB];
    int chunk = (E + gridDim.x - 1) / gridDim.x;
    int lo = blockIdx.x * chunk, hi = min(lo + chunk, E);
    for (int i = threadIdx.x; i < B; i += blockDim.x) { lc[i] = 0; lfill[i] = 0; }
    __syncthreads();
    for (int e = lo + threadIdx.x; e < hi; e += blockDim.x)
        atomicAdd(&lc[dst[e] >> NPB_SHIFT], 1);
    __syncthreads();
    for (int i = threadIdx.x; i < B; i += blockDim.x)
        lbase[i] = lc[i] ? atomicAdd(&cursor[i], lc[i]) : 0;
    __syncthreads();
    for (int e = lo + threadIdx.x; e < hi; e += blockDim.x) {
        int t = dst[e];
        int b = t >> NPB_SHIFT;
        int pos = lbase[b] + atomicAdd(&lfill[b], 1);
        adjB[pos] = make_int2(src[e] | ((t & (NPB - 1)) << 20), __float_as_int(w[e]));
    }
}

// ---------------------------------------------------------------------------
// per-bucket LDS counting sort: bucket-grouped adjB -> node-grouped adj,
// and emit rowStart. Reads coalesced; writes scattered only within the
// bucket's ~12KB window (L2 absorbs; whole window is dirtied anyway).
// ---------------------------------------------------------------------------
__global__ __launch_bounds__(256) void sort_bucket_kernel(
        const int2* __restrict__ adjB, const int* __restrict__ bucketStart,
        int2* __restrict__ adj, int* __restrict__ rowStart, int N) {
    __shared__ int cnt[NPB];
    __shared__ int pre[NPB];
    __shared__ int fill[NPB];
    int b = blockIdx.x;
    int beg = bucketStart[b], end = bucketStart[b + 1];
    int t = threadIdx.x;
    if (t < NPB) { cnt[t] = 0; fill[t] = 0; }
    __syncthreads();
    for (int e = beg + t; e < end; e += blockDim.x)
        atomicAdd(&cnt[((unsigned)adjB[e].x) >> 20], 1);
    __syncthreads();
    // exclusive scan of cnt[NPB] (Hillis-Steele in LDS)
    if (t < NPB) pre[t] = cnt[t];
    __syncthreads();
    for (int st = 1; st < NPB; st <<= 1) {
        int v = (t < NPB && t >= st) ? pre[t - st] : 0;
        __syncthreads();
        if (t < NPB) pre[t] += v;
        __syncthreads();
    }
    if (t < NPB) {
        int node = b * NPB + t;
        if (node < N) rowStart[node] = beg + ((t == 0) ? 0 : pre[t - 1]);
    }
    __syncthreads();
    for (int e = beg + t; e < end; e += blockDim.x) {
        int2 a = adjB[e];
        int dL = ((unsigned)a.x) >> 20;
        int base = beg + ((dL == 0) ? 0 : pre[dL - 1]);
        int pos = base + atomicAdd(&fill[dL], 1);
        adj[pos] = make_int2(a.x & 0xFFFFF, a.y);
    }
}

// ---------------------------------------------------------------------------
// Tiled row GEMM -> bf16 packed proj. Block = 64 rows; A staged transposed
// in LDS; theta in LDS; thread computes 4x4 block; output rows stored as
// 64 x bf16 (128B rows).
// ---------------------------------------------------------------------------
__global__ __launch_bounds__(256) void rowgemm_bf16_kernel(const float* __restrict__ A,
                                                           const float* __restrict__ theta,
                                                           unsigned short* __restrict__ proj16,
                                                           int N) {
    __shared__ float th[D * D];
    __shared__ float at[D][68];
    int t = threadIdx.x;
    int rowBase = blockIdx.x * 64;

#pragma unroll
    for (int i = 0; i < 4; ++i) {
        int f = t + i * 256;
        ((float4*)th)[f] = ((const float4*)theta)[f];
    }
#pragma unroll
    for (int i = 0; i < 4; ++i) {
        int f = t + i * 256;
        int row = f >> 4;
        int kv = f & 15;
        float4 v = make_float4(0.f, 0.f, 0.f, 0.f);
        if (rowBase + row < N) v = *(const float4*)&A[(size_t)(rowBase + row) * D + kv * 4];
        at[kv * 4 + 0][row] = v.x;
        at[kv * 4 + 1][row] = v.y;
        at[kv * 4 + 2][row] = v.z;
        at[kv * 4 + 3][row] = v.w;
    }
    __syncthreads();

    int c0 = (t & 15) * 4;
    int r0 = (t >> 4) * 4;
    float4 acc0 = make_float4(0.f, 0.f, 0.f, 0.f);
    float4 acc1 = acc0, acc2 = acc0, acc3 = acc0;

#pragma unroll
    for (int k = 0; k < D; ++k) {
        float4 bv = *(const float4*)&th[k * D + c0];
        float4 av = *(const float4*)&at[k][r0];
        acc0.x += av.x * bv.x; acc0.y += av.x * bv.y; acc0.z += av.x * bv.z; acc0.w += av.x * bv.w;
        acc1.x += av.y * bv.x; acc1.y += av.y * bv.y; acc1.z += av.y * bv.z; acc1.w += av.y * bv.w;
        acc2.x += av.z * bv.x; acc2.y += av.z * bv.y; acc2.z += av.z * bv.z; acc2.w += av.z * bv.w;
        acc3.x += av.w * bv.x; acc3.y += av.w * bv.y; acc3.z += av.w * bv.z; acc3.w += av.w * bv.w;
    }

    float4 accs[4] = {acc0, acc1, acc2, acc3};
#pragma unroll
    for (int i = 0; i < 4; ++i) {
        int r = rowBase + r0 + i;
        if (r < N) {
            unsigned lo = f2bf(accs[i].x) | (f2bf(accs[i].y) << 16);
            unsigned hi = f2bf(accs[i].z) | (f2bf(accs[i].w) << 16);
            *(uint2*)&proj16[(size_t)r * D + c0] = make_uint2(lo, hi);
        }
    }
}

// ---------------------------------------------------------------------------
// gather: one wave per node. adj entries loaded 64/wave coalesced; each
// HALF-wave (32 lanes x 4B) reads one 128B bf16 row -> 2 edges per step.
// Lane k&31 owns dims {2k,2k+1}; cross-half shfl-reduce at the end.
// ---------------------------------------------------------------------------
__global__ void gather_kernel(const int* __restrict__ rowStart, const int2* __restrict__ adj,
                              const unsigned* __restrict__ projU, float* __restrict__ out, int N) {
    int wid = (blockIdx.x * blockDim.x + threadIdx.x) >> 6;
    int lane = threadIdx.x & 63;
    if (wid >= N) return;
    int beg = rowStart[wid];
    int end = rowStart[wid + 1];
    int half = lane >> 5;
    int k = lane & 31;

    float2 accA = make_float2(0.f, 0.f);
    float2 accB = make_float2(0.f, 0.f);

    for (int base = beg; base < end; base += 64) {
        int cnt = min(64, end - base);
        int2 a = make_int2(0, 0);
        if (lane < cnt) a = adj[base + lane];
        int pairs = (cnt + 1) >> 1;
        int j = 0;
        for (; j + 1 < pairs; j += 2) {
            int ea = 2 * j + half;          // <= 61
            int eb = ea + 2;                // <= 63
            int   sa = __shfl(a.x, ea, 64);
            float wa = __int_as_float(__shfl(a.y, ea, 64));
            int   sb = __shfl(a.x, eb, 64);
            float wb = __int_as_float(__shfl(a.y, eb, 64));
            unsigned pa = projU[(size_t)sa * 32 + k];
            unsigned pb = projU[(size_t)sb * 32 + k];
            accA.x += wa * __uint_as_float(pa << 16);
            accA.y += wa * __uint_as_float(pa & 0xFFFF0000u);
            accB.x += wb * __uint_as_float(pb << 16);
            accB.y += wb * __uint_as_float(pb & 0xFFFF0000u);
        }
        if (j < pairs) {
            int ea = 2 * j + half;
            int   sa = __shfl(a.x, ea, 64);
            float wa = __int_as_float(__shfl(a.y, ea, 64));  // 0 beyond cnt
            unsigned pa = projU[(size_t)sa * 32 + k];
            accA.x += wa * __uint_as_float(pa << 16);
            accA.y += wa * __uint_as_float(pa & 0xFFFF0000u);
        }
    }
    float2 acc = make_float2(accA.x + accB.x, accA.y + accB.y);
    acc.x += __shfl(acc.x, lane ^ 32, 64);
    acc.y += __shfl(acc.y, lane ^ 32, 64);
    if (half == 0)
        *(float2*)&out[(size_t)wid * D + 2 * k] = acc;   // 32 lanes x 8B coalesced
}

// ---------------------------------------------------------------------------
// fallback path (atomic scatter + fp32 row GEMM) if ws/shape checks fail
// ---------------------------------------------------------------------------
__global__ void scatter_kernel(const int* __restrict__ src, const int* __restrict__ dst,
                               const float* __restrict__ w, const float* __restrict__ data,
                               float* __restrict__ agg, int E) {
    int tid = blockIdx.x * blockDim.x + threadIdx.x;
    int e = tid >> 6;
    int d = tid & 63;
    if (e >= E) return;
    float val = w[e] * data[(size_t)src[e] * D + d];
    atomicAdd(&agg[(size_t)dst[e] * D + d], val);
}

__global__ __launch_bounds__(256) void rowgemm_f32_kernel(const float* __restrict__ A,
                                                          const float* __restrict__ theta,
                                                          float* __restrict__ out, int N) {
    __shared__ float th[D * D];
    __shared__ float at[D][68];
    int t = threadIdx.x;
    int rowBase = blockIdx.x * 64;
#pragma unroll
    for (int i = 0; i < 4; ++i) {
        int f = t + i * 256;
        ((float4*)th)[f] = ((const float4*)theta)[f];
    }
#pragma unroll
    for (int i = 0; i < 4; ++i) {
        int f = t + i * 256;
        int row = f >> 4;
        int kv = f & 15;
        float4 v = make_float4(0.f, 0.f, 0.f, 0.f);
        if (rowBase + row < N) v = *(const float4*)&A[(size_t)(rowBase + row) * D + kv * 4];
        at[kv * 4 + 0][row] = v.x;
        at[kv * 4 + 1][row] = v.y;
        at[kv * 4 + 2][row] = v.z;
        at[kv * 4 + 3][row] = v.w;
    }
    __syncthreads();
    int c0 = (t & 15) * 4;
    int r0 = (t >> 4) * 4;
    float4 acc0 = make_float4(0.f, 0.f, 0.f, 0.f);
    float4 acc1 = acc0, acc2 = acc0, acc3 = acc0;
#pragma unroll
    for (int kk = 0; kk < D; ++kk) {
        float4 bv = *(const float4*)&th[kk * D + c0];
        float4 av = *(const float4*)&at[kk][r0];
        acc0.x += av.x * bv.x; acc0.y += av.x * bv.y; acc0.z += av.x * bv.z; acc0.w += av.x * bv.w;
        acc1.x += av.y * bv.x; acc1.y += av.y * bv.y; acc1.z += av.y * bv.z; acc1.w += av.y * bv.w;
        acc2.x += av.z * bv.x; acc2.y += av.z * bv.y; acc2.z += av.z * bv.z; acc2.w += av.z * bv.w;
        acc3.x += av.w * bv.x; acc3.y += av.w * bv.y; acc3.z += av.w * bv.z; acc3.w += av.w * bv.w;
    }
    float4 accs[4] = {acc0, acc1, acc2, acc3};
#pragma unroll
    for (int i = 0; i < 4; ++i) {
        int r = rowBase + r0 + i;
        if (r < N) *(float4*)&out[(size_t)r * D + c0] = accs[i];
    }
}

extern "C" void kernel_launch(void* const* d_in, const int* in_sizes, int n_in,
                              void* d_out, int out_size, void* d_ws, size_t ws_size,
                              hipStream_t stream) {
    const int*   src   = (const int*)d_in[0];
    const int*   dst   = (const int*)d_in[1];
    const float* w     = (const float*)d_in[2];
    const float* data  = (const float*)d_in[3];
    const float* theta = (const float*)d_in[4];
    const int E = in_sizes[0];
    const int N = in_sizes[3] / D;
    float* out = (float*)d_out;

    const int B = (N + NPB - 1) / NPB;

    // ws layout: proj16 (bf16) | adjB | adj | cnt[B] | bucketStart[B+1] |
    //            cursor[B] | rowStart[N+1]
    size_t projBytes = (size_t)N * D * 2;                 // 16-aligned for N*D mult of 8
    size_t need = projBytes + (size_t)E * 8 * 2
                + ((size_t)3 * B + 2) * 4 + ((size_t)N + 1) * 4 + 256;

    if (ws_size >= need && N < (1 << 20) && B <= MAXB) {
        unsigned short* proj16 = (unsigned short*)d_ws;
        int2* adjB        = (int2*)((char*)d_ws + projBytes);
        int2* adj         = adjB + E;
        int*  cnt         = (int*)(adj + E);
        int*  bucketStart = cnt + B;
        int*  cursor      = bucketStart + (B + 1);
        int*  rowStart    = cursor + B;

        zero_i_kernel<<<(B + 255) / 256, 256, 0, stream>>>(cnt, B);
        hist_bucket_kernel<<<SCATTER_BLOCKS, SCATTER_T, 0, stream>>>(dst, cnt, E, B);
        scan_bucket_kernel<<<1, MAXB, 0, stream>>>(cnt, bucketStart, cursor, rowStart + N, B, E);
        bucket_scatter_kernel<<<SCATTER_BLOCKS, SCATTER_T, 0, stream>>>(src, dst, w, cursor, adjB, E, B);
        sort_bucket_kernel<<<B, 256, 0, stream>>>(adjB, bucketStart, adj, rowStart, N);
        rowgemm_bf16_kernel<<<(N + 63) / 64, 256, 0, stream>>>(data, theta, proj16, N);
        gather_kernel<<<(N + 3) / 4, 256, 0, stream>>>(rowStart, adj, (const unsigned*)proj16, out, N);
    } else {
        float* agg = (float*)d_ws;
        int n4 = (N * D) / 4;
        zero_f4_kernel<<<(n4 + 255) / 256, 256, 0, stream>>>((float4*)agg, n4);
        long long total = (long long)E * D;
        scatter_kernel<<<(int)((total + 255) / 256), 256, 0, stream>>>(src, dst, w, data, agg, E);
        rowgemm_f32_kernel<<<(N + 63) / 64, 256, 0, stream>>>(agg, theta, out, N);
    }
}

// Round 6
// 208.322 us; speedup vs baseline: 3.3443x; 1.1519x over previous
//
#include <hip/hip_runtime.h>

#define D 64
#define NPB 128              // nodes per bucket (dstLocal: 7 bits)
#define NPB_SHIFT 7
#define MAXB 1024            // bound on bucket count B = ceil(N/NPB)
#define SCATTER_BLOCKS 256
#define SCATTER_T 256

// round-to-nearest-even fp32 -> bf16 (values are finite/normal here)
__device__ inline unsigned f2bf(float f) {
    unsigned u = __float_as_uint(f);
    return (u + 0x7FFFu + ((u >> 16) & 1u)) >> 16;
}

// ---------------------------------------------------------------------------
// zero helpers (ws is poisoned 0xAA every launch)
// ---------------------------------------------------------------------------
__global__ void zero_i_kernel(int* __restrict__ p, int n) {
    int i = blockIdx.x * blockDim.x + threadIdx.x;
    if (i < n) p[i] = 0;
}
__global__ void zero_f4_kernel(float4* __restrict__ p, int n4) {
    int i = blockIdx.x * blockDim.x + threadIdx.x;
    if (i < n4) p[i] = make_float4(0.f, 0.f, 0.f, 0.f);
}

// ---------------------------------------------------------------------------
// bucket histogram: LDS-staged, then one global atomic per (block,bucket)
// ---------------------------------------------------------------------------
__global__ __launch_bounds__(SCATTER_T) void hist_bucket_kernel(const int* __restrict__ dst,
                                                                int* __restrict__ cnt,
                                                                int E, int B) {
    __shared__ int lc[MAXB];
    for (int i = threadIdx.x; i < B; i += blockDim.x) lc[i] = 0;
    __syncthreads();
    int chunk = (E + gridDim.x - 1) / gridDim.x;
    int lo = blockIdx.x * chunk, hi = min(lo + chunk, E);
    for (int e = lo + threadIdx.x; e < hi; e += blockDim.x)
        atomicAdd(&lc[dst[e] >> NPB_SHIFT], 1);
    __syncthreads();
    for (int i = threadIdx.x; i < B; i += blockDim.x)
        if (lc[i]) atomicAdd(&cnt[i], lc[i]);
}

// ---------------------------------------------------------------------------
// exclusive scan of bucket counts (single block of MAXB threads)
// writes bucketStart[0..B], cursor[0..B), rowStart[N] = E
// ---------------------------------------------------------------------------
__global__ __launch_bounds__(MAXB) void scan_bucket_kernel(const int* __restrict__ cnt,
                                                           int* __restrict__ bucketStart,
                                                           int* __restrict__ cursor,
                                                           int* __restrict__ rowStartN,
                                                           int B, int E) {
    __shared__ int sd[MAXB];
    int t = threadIdx.x;
    sd[t] = (t < B) ? cnt[t] : 0;
    __syncthreads();
    for (int st = 1; st < MAXB; st <<= 1) {
        int v = (t >= st) ? sd[t - st] : 0;
        __syncthreads();
        sd[t] += v;
        __syncthreads();
    }
    if (t < B) {
        int ex = (t == 0) ? 0 : sd[t - 1];
        bucketStart[t] = ex;
        cursor[t] = ex;
    }
    if (t == 0) { bucketStart[B] = E; *rowStartN = E; }
}

// ---------------------------------------------------------------------------
// bucket scatter (two-pass per block): LDS chunk histogram -> reserve
// contiguous per-bucket ranges (1 global atomic per block x bucket) ->
// write. Entries land in ~48-96B contiguous runs so L2 merges lines.
// Packing: x = src | dstLocal<<20, y = w bits.
// ---------------------------------------------------------------------------
__global__ __launch_bounds__(SCATTER_T) void bucket_scatter_kernel(
        const int* __restrict__ src, const int* __restrict__ dst,
        const float* __restrict__ w, int* __restrict__ cursor,
        int2* __restrict__ adjB, int E, int B) {
    __shared__ int lc[MAXB];
    __shared__ int lbase[MAXB];
    __shared__ int lfill[MAXB];
    int chunk = (E + gridDim.x - 1) / gridDim.x;
    int lo = blockIdx.x * chunk, hi = min(lo + chunk, E);
    for (int i = threadIdx.x; i < B; i += blockDim.x) { lc[i] = 0; lfill[i] = 0; }
    __syncthreads();
    for (int e = lo + threadIdx.x; e < hi; e += blockDim.x)
        atomicAdd(&lc[dst[e] >> NPB_SHIFT], 1);
    __syncthreads();
    for (int i = threadIdx.x; i < B; i += blockDim.x)
        lbase[i] = lc[i] ? atomicAdd(&cursor[i], lc[i]) : 0;
    __syncthreads();
    for (int e = lo + threadIdx.x; e < hi; e += blockDim.x) {
        int t = dst[e];
        int b = t >> NPB_SHIFT;
        int pos = lbase[b] + atomicAdd(&lfill[b], 1);
        adjB[pos] = make_int2(src[e] | ((t & (NPB - 1)) << 20), __float_as_int(w[e]));
    }
}

// ---------------------------------------------------------------------------
// per-bucket LDS counting sort: bucket-grouped adjB -> node-grouped adj,
// and emit rowStart. Reads coalesced; writes scattered only within the
// bucket's ~12KB window (L2 absorbs).
// ---------------------------------------------------------------------------
__global__ __launch_bounds__(256) void sort_bucket_kernel(
        const int2* __restrict__ adjB, const int* __restrict__ bucketStart,
        int2* __restrict__ adj, int* __restrict__ rowStart, int N) {
    __shared__ int cnt[NPB];
    __shared__ int pre[NPB];
    __shared__ int fill[NPB];
    int b = blockIdx.x;
    int beg = bucketStart[b], end = bucketStart[b + 1];
    int t = threadIdx.x;
    if (t < NPB) { cnt[t] = 0; fill[t] = 0; }
    __syncthreads();
    for (int e = beg + t; e < end; e += blockDim.x)
        atomicAdd(&cnt[((unsigned)adjB[e].x) >> 20], 1);
    __syncthreads();
    if (t < NPB) pre[t] = cnt[t];
    __syncthreads();
    for (int st = 1; st < NPB; st <<= 1) {
        int v = (t < NPB && t >= st) ? pre[t - st] : 0;
        __syncthreads();
        if (t < NPB) pre[t] += v;
        __syncthreads();
    }
    if (t < NPB) {
        int node = b * NPB + t;
        if (node < N) rowStart[node] = beg + ((t == 0) ? 0 : pre[t - 1]);
    }
    __syncthreads();
    for (int e = beg + t; e < end; e += blockDim.x) {
        int2 a = adjB[e];
        int dL = ((unsigned)a.x) >> 20;
        int base = beg + ((dL == 0) ? 0 : pre[dL - 1]);
        int pos = base + atomicAdd(&fill[dL], 1);
        adj[pos] = make_int2(a.x & 0xFFFFF, a.y);
    }
}

// ---------------------------------------------------------------------------
// Tiled row GEMM -> bf16 packed proj. Block = 64 rows; A staged transposed
// in LDS; theta in LDS; thread computes 4x4 block.
// __launch_bounds__(256,4): cap VGPR at 128 (r5 post-mortem: the bf16-pack
// epilogue made the scheduler hoist the full k-unroll -> 252 VGPR, 9%
// occupancy, 60us). unroll 16 keeps ILP within the cap without spilling.
// ---------------------------------------------------------------------------
__global__ __launch_bounds__(256, 4) void rowgemm_bf16_kernel(const float* __restrict__ A,
                                                              const float* __restrict__ theta,
                                                              unsigned short* __restrict__ proj16,
                                                              int N) {
    __shared__ float th[D * D];
    __shared__ float at[D][68];
    int t = threadIdx.x;
    int rowBase = blockIdx.x * 64;

#pragma unroll
    for (int i = 0; i < 4; ++i) {
        int f = t + i * 256;
        ((float4*)th)[f] = ((const float4*)theta)[f];
    }
#pragma unroll
    for (int i = 0; i < 4; ++i) {
        int f = t + i * 256;
        int row = f >> 4;
        int kv = f & 15;
        float4 v = make_float4(0.f, 0.f, 0.f, 0.f);
        if (rowBase + row < N) v = *(const float4*)&A[(size_t)(rowBase + row) * D + kv * 4];
        at[kv * 4 + 0][row] = v.x;
        at[kv * 4 + 1][row] = v.y;
        at[kv * 4 + 2][row] = v.z;
        at[kv * 4 + 3][row] = v.w;
    }
    __syncthreads();

    int c0 = (t & 15) * 4;
    int r0 = (t >> 4) * 4;
    float4 acc0 = make_float4(0.f, 0.f, 0.f, 0.f);
    float4 acc1 = acc0, acc2 = acc0, acc3 = acc0;

#pragma unroll 16
    for (int k = 0; k < D; ++k) {
        float4 bv = *(const float4*)&th[k * D + c0];
        float4 av = *(const float4*)&at[k][r0];
        acc0.x += av.x * bv.x; acc0.y += av.x * bv.y; acc0.z += av.x * bv.z; acc0.w += av.x * bv.w;
        acc1.x += av.y * bv.x; acc1.y += av.y * bv.y; acc1.z += av.y * bv.z; acc1.w += av.y * bv.w;
        acc2.x += av.z * bv.x; acc2.y += av.z * bv.y; acc2.z += av.z * bv.z; acc2.w += av.z * bv.w;
        acc3.x += av.w * bv.x; acc3.y += av.w * bv.y; acc3.z += av.w * bv.z; acc3.w += av.w * bv.w;
    }

    float4 accs[4] = {acc0, acc1, acc2, acc3};
#pragma unroll
    for (int i = 0; i < 4; ++i) {
        int r = rowBase + r0 + i;
        if (r < N) {
            unsigned lo = f2bf(accs[i].x) | (f2bf(accs[i].y) << 16);
            unsigned hi = f2bf(accs[i].z) | (f2bf(accs[i].w) << 16);
            *(uint2*)&proj16[(size_t)r * D + c0] = make_uint2(lo, hi);
        }
    }
}

// ---------------------------------------------------------------------------
// gather: one wave per node. adj entries loaded 64/wave coalesced; each
// HALF-wave (32 lanes x 4B) reads one 128B bf16 row -> 2 edges per step.
// Lane k owns dims {2k,2k+1}; cross-half shfl-reduce at the end.
// ---------------------------------------------------------------------------
__global__ void gather_kernel(const int* __restrict__ rowStart, const int2* __restrict__ adj,
                              const unsigned* __restrict__ projU, float* __restrict__ out, int N) {
    int wid = (blockIdx.x * blockDim.x + threadIdx.x) >> 6;
    int lane = threadIdx.x & 63;
    if (wid >= N) return;
    int beg = rowStart[wid];
    int end = rowStart[wid + 1];
    int half = lane >> 5;
    int k = lane & 31;

    float2 accA = make_float2(0.f, 0.f);
    float2 accB = make_float2(0.f, 0.f);

    for (int base = beg; base < end; base += 64) {
        int cnt = min(64, end - base);
        int2 a = make_int2(0, 0);
        if (lane < cnt) a = adj[base + lane];
        int pairs = (cnt + 1) >> 1;
        int j = 0;
        for (; j + 1 < pairs; j += 2) {
            int ea = 2 * j + half;
            int eb = ea + 2;
            int   sa = __shfl(a.x, ea, 64);
            float wa = __int_as_float(__shfl(a.y, ea, 64));
            int   sb = __shfl(a.x, eb, 64);
            float wb = __int_as_float(__shfl(a.y, eb, 64));
            unsigned pa = projU[(size_t)sa * 32 + k];
            unsigned pb = projU[(size_t)sb * 32 + k];
            accA.x += wa * __uint_as_float(pa << 16);
            accA.y += wa * __uint_as_float(pa & 0xFFFF0000u);
            accB.x += wb * __uint_as_float(pb << 16);
            accB.y += wb * __uint_as_float(pb & 0xFFFF0000u);
        }
        if (j < pairs) {
            int ea = 2 * j + half;
            int   sa = __shfl(a.x, ea, 64);
            float wa = __int_as_float(__shfl(a.y, ea, 64));  // 0 beyond cnt
            unsigned pa = projU[(size_t)sa * 32 + k];
            accA.x += wa * __uint_as_float(pa << 16);
            accA.y += wa * __uint_as_float(pa & 0xFFFF0000u);
        }
    }
    float2 acc = make_float2(accA.x + accB.x, accA.y + accB.y);
    acc.x += __shfl(acc.x, lane ^ 32, 64);
    acc.y += __shfl(acc.y, lane ^ 32, 64);
    if (half == 0)
        *(float2*)&out[(size_t)wid * D + 2 * k] = acc;   // 32 lanes x 8B coalesced
}

// ---------------------------------------------------------------------------
// fallback path (atomic scatter + fp32 row GEMM) if ws/shape checks fail
// ---------------------------------------------------------------------------
__global__ void scatter_kernel(const int* __restrict__ src, const int* __restrict__ dst,
                               const float* __restrict__ w, const float* __restrict__ data,
                               float* __restrict__ agg, int E) {
    int tid = blockIdx.x * blockDim.x + threadIdx.x;
    int e = tid >> 6;
    int d = tid & 63;
    if (e >= E) return;
    float val = w[e] * data[(size_t)src[e] * D + d];
    atomicAdd(&agg[(size_t)dst[e] * D + d], val);
}

__global__ __launch_bounds__(256, 4) void rowgemm_f32_kernel(const float* __restrict__ A,
                                                             const float* __restrict__ theta,
                                                             float* __restrict__ out, int N) {
    __shared__ float th[D * D];
    __shared__ float at[D][68];
    int t = threadIdx.x;
    int rowBase = blockIdx.x * 64;
#pragma unroll
    for (int i = 0; i < 4; ++i) {
        int f = t + i * 256;
        ((float4*)th)[f] = ((const float4*)theta)[f];
    }
#pragma unroll
    for (int i = 0; i < 4; ++i) {
        int f = t + i * 256;
        int row = f >> 4;
        int kv = f & 15;
        float4 v = make_float4(0.f, 0.f, 0.f, 0.f);
        if (rowBase + row < N) v = *(const float4*)&A[(size_t)(rowBase + row) * D + kv * 4];
        at[kv * 4 + 0][row] = v.x;
        at[kv * 4 + 1][row] = v.y;
        at[kv * 4 + 2][row] = v.z;
        at[kv * 4 + 3][row] = v.w;
    }
    __syncthreads();
    int c0 = (t & 15) * 4;
    int r0 = (t >> 4) * 4;
    float4 acc0 = make_float4(0.f, 0.f, 0.f, 0.f);
    float4 acc1 = acc0, acc2 = acc0, acc3 = acc0;
#pragma unroll 16
    for (int kk = 0; kk < D; ++kk) {
        float4 bv = *(const float4*)&th[kk * D + c0];
        float4 av = *(const float4*)&at[kk][r0];
        acc0.x += av.x * bv.x; acc0.y += av.x * bv.y; acc0.z += av.x * bv.z; acc0.w += av.x * bv.w;
        acc1.x += av.y * bv.x; acc1.y += av.y * bv.y; acc1.z += av.y * bv.z; acc1.w += av.y * bv.w;
        acc2.x += av.z * bv.x; acc2.y += av.z * bv.y; acc2.z += av.z * bv.z; acc2.w += av.z * bv.w;
        acc3.x += av.w * bv.x; acc3.y += av.w * bv.y; acc3.z += av.w * bv.z; acc3.w += av.w * bv.w;
    }
    float4 accs[4] = {acc0, acc1, acc2, acc3};
#pragma unroll
    for (int i = 0; i < 4; ++i) {
        int r = rowBase + r0 + i;
        if (r < N) *(float4*)&out[(size_t)r * D + c0] = accs[i];
    }
}

extern "C" void kernel_launch(void* const* d_in, const int* in_sizes, int n_in,
                              void* d_out, int out_size, void* d_ws, size_t ws_size,
                              hipStream_t stream) {
    const int*   src   = (const int*)d_in[0];
    const int*   dst   = (const int*)d_in[1];
    const float* w     = (const float*)d_in[2];
    const float* data  = (const float*)d_in[3];
    const float* theta = (const float*)d_in[4];
    const int E = in_sizes[0];
    const int N = in_sizes[3] / D;
    float* out = (float*)d_out;

    const int B = (N + NPB - 1) / NPB;

    // ws layout: proj16 (bf16) | adjB | adj | cnt[B] | bucketStart[B+1] |
    //            cursor[B] | rowStart[N+1]
    size_t projBytes = (size_t)N * D * 2;
    size_t need = projBytes + (size_t)E * 8 * 2
                + ((size_t)3 * B + 2) * 4 + ((size_t)N + 1) * 4 + 256;

    if (ws_size >= need && N < (1 << 20) && B <= MAXB) {
        unsigned short* proj16 = (unsigned short*)d_ws;
        int2* adjB        = (int2*)((char*)d_ws + projBytes);
        int2* adj         = adjB + E;
        int*  cnt         = (int*)(adj + E);
        int*  bucketStart = cnt + B;
        int*  cursor      = bucketStart + (B + 1);
        int*  rowStart    = cursor + B;

        zero_i_kernel<<<(B + 255) / 256, 256, 0, stream>>>(cnt, B);
        hist_bucket_kernel<<<SCATTER_BLOCKS, SCATTER_T, 0, stream>>>(dst, cnt, E, B);
        scan_bucket_kernel<<<1, MAXB, 0, stream>>>(cnt, bucketStart, cursor, rowStart + N, B, E);
        bucket_scatter_kernel<<<SCATTER_BLOCKS, SCATTER_T, 0, stream>>>(src, dst, w, cursor, adjB, E, B);
        sort_bucket_kernel<<<B, 256, 0, stream>>>(adjB, bucketStart, adj, rowStart, N);
        rowgemm_bf16_kernel<<<(N + 63) / 64, 256, 0, stream>>>(data, theta, proj16, N);
        gather_kernel<<<(N + 3) / 4, 256, 0, stream>>>(rowStart, adj, (const unsigned*)proj16, out, N);
    } else {
        float* agg = (float*)d_ws;
        int n4 = (N * D) / 4;
        zero_f4_kernel<<<(n4 + 255) / 256, 256, 0, stream>>>((float4*)agg, n4);
        long long total = (long long)E * D;
        scatter_kernel<<<(int)((total + 255) / 256), 256, 0, stream>>>(src, dst, w, data, agg, E);
        rowgemm_f32_kernel<<<(N + 63) / 64, 256, 0, stream>>>(agg, theta, out, N);
    }
}